// Round 16
// baseline (353.121 us; speedup 1.0000x reference)
//
#include <hip/hip_runtime.h>

// RecursiveEncoder on MI355X. B=16, H=256, S=16, C=5, L=6, N_LEAF=15625, N_INT=3906.
// R21: launch-count + leaf TLP. R20 budget: leaf 67 + l5 65 = 132us measured;
//      tail kernels ~35-40us by estimate -> ~170us in ~10 dependent-launch
//      boundaries (~16us each; also explains why software barriers never paid).
//      (1) dest_kernel launch deleted: leaf derives its l5 slot->leaf-row map
//      inline from buckets+counters (inverse of dest's scatter; rsrc array
//      gone); the l<5 wdest scatter rides as blocks >=2048 of the same launch.
//      11 -> 10 launches. (2) leaf grid 1024->2048 (direct R17-form, VGPR~52,
//      no LDS): 32 waves/CU for the latency-bound gathered reads.
//      prep/bucket/l5(pairing,DEPTH=2)/level_direct/head unchanged from R20.

#define B_ 16
#define H_ 256
#define NLEAF 15625
#define NINT 3906
#define RND128(x) (((x) + 127) & ~127)

typedef __bf16 bf16_t;
typedef bf16_t bf16x8 __attribute__((ext_vector_type(8)));
typedef bf16_t bf16x4 __attribute__((ext_vector_type(4)));
typedef float f32x4 __attribute__((ext_vector_type(4)));

__device__ __forceinline__ void gl2lds16(const bf16_t* g, bf16_t* l) {
  __builtin_amdgcn_global_load_lds((const __attribute__((address_space(1))) void*)g,
                                   (__attribute__((address_space(3))) void*)l,
                                   16, 0, 0);
}

// Wt K-panel layout: panel (t*2+half) of 128 h-rows; elem (h,k) at
// panel*40*4096 + (k>>5)*4096 + (h&127)*32 + (chunk^swz)*8 + (k&7).
__global__ __launch_bounds__(256) void prep_kernel(const float* __restrict__ W_node,
                                                   bf16_t* __restrict__ Wt,
                                                   int* __restrict__ counters) {
  if (blockIdx.x == 0 && threadIdx.x < 18) counters[threadIdx.x] = 0;
  const int t = blockIdx.x / 80;
  const int kc = blockIdx.x % 80;
  const int h = threadIdx.x;
  const int half = h >> 7, r = h & 127;
  const int sw = (r >> 1) & 3;
  const float* srcp = W_node + (size_t)t * 1280 * 256 + h;
  bf16_t* base = Wt + ((size_t)(t * 2 + half) * 40) * 4096 + r * 32;
#pragma unroll
  for (int k0 = kc * 16; k0 < kc * 16 + 16; k0 += 8) {
    bf16x8 v;
#pragma unroll
    for (int j = 0; j < 8; ++j) v[j] = (bf16_t)srcp[(size_t)(k0 + j) * 256];
    const int ks = k0 >> 5;
    const int q = (k0 >> 3) & 3;
    *(bf16x8*)(base + (size_t)ks * 4096 + ((q ^ sw) << 3)) = v;
  }
}

// LDS-aggregated bucketing (block-local order preserved -> decent locality).
__global__ __launch_bounds__(256) void bucket_kernel(const int* __restrict__ node_type,
                                                     int* __restrict__ counters,
                                                     int2* __restrict__ buckets) {
  __shared__ int lcnt[18];
  __shared__ int lbase[18];
  const int tid = threadIdx.x;
  if (tid < 18) lcnt[tid] = 0;
  __syncthreads();

  int idx = blockIdx.x * 256 + tid;
  bool active = idx < B_ * NINT;
  int t = 0, key = 0, mypos = 0;
  int2 e;
  int base = 0, nl_cap = 0;
  if (active) {
    int b = idx / NINT;
    int j = idx - b * NINT;
    int l, off;
    if (j >= 781)      { l = 5; off = 781; }
    else if (j >= 156) { l = 4; off = 156; }
    else if (j >= 31)  { l = 3; off = 31; }
    else if (j >= 6)   { l = 2; off = 6; }
    else if (j >= 1)   { l = 1; off = 1; }
    else               { l = 0; off = 0; }
    const int n_tab[6]    = {1, 5, 25, 125, 625, 3125};
    const int nn_tab[6]   = {5, 25, 125, 625, 3125, 15625};
    const int base_tab[6] = {0, 48, 288, 1488, 7488, 37488};
    int n_l = n_tab[l], nn = nn_tab[l];
    t = node_type[idx];
    int i = j - off;
    e.x = b * n_l + i;
    e.y = b * nn + 5 * i;
    base = base_tab[l];
    nl_cap = B_ * n_l;
    key = l * 3 + t;
    mypos = atomicAdd(&lcnt[key], 1);
  }
  __syncthreads();
  if (tid < 18) {
    int c = lcnt[tid];
    lbase[tid] = c ? atomicAdd(&counters[tid], c) : 0;
  }
  __syncthreads();
  if (active) {
    buckets[base + t * nl_cap + lbase[key] + mypos] = e;
  }
}

// MFMA leaf + folded wdest scatter. Blocks < 2048: leaf compute (wave handles
// 16 consecutive G_5 chunk-slots; leaf row derived INLINE from buckets via the
// inverse of dest's mapping). Blocks >= 2048: the l<5 wdest scatter (needs
// only bucket output, same dependency as leaf).
__global__ __launch_bounds__(256) void leafdest_kernel(
    const float* __restrict__ leaf_box, const float* __restrict__ leaf_sem,
    const float* __restrict__ W_box, const float* __restrict__ b_box,
    const float* __restrict__ W_sem, const float* __restrict__ b_sem,
    const int2* __restrict__ buckets, const int* __restrict__ counters,
    int* __restrict__ wdest_all, bf16_t* __restrict__ g5) {
  if (blockIdx.x >= 2048) {
    // ---- dest portion: parents at levels 0..4 -> children wdest slots ----
    int flat = (blockIdx.x - 2048) * 256 + threadIdx.x;
    if (flat >= 37488) return;
    int l, base, cap, coff;
    if (flat >= 7488)       { l = 4; base = 7488;  cap = 10000; coff = 12480; }
    else if (flat >= 1488)  { l = 3; base = 1488;  cap = 2000;  coff = 2480; }
    else if (flat >= 288)   { l = 2; base = 288;   cap = 400;   coff = 480; }
    else if (flat >= 48)    { l = 1; base = 48;    cap = 80;    coff = 80; }
    else                    { l = 0; base = 0;     cap = 16;    coff = 0; }
    int rel = flat - base;
    int t = (rel >= 2 * cap) ? 2 : (rel >= cap ? 1 : 0);
    int s = rel - t * cap;
    const int* c3 = counters + l * 3;
    if (s >= c3[t]) return;
    int pfxr = (t > 0 ? RND128(c3[0]) : 0) + (t > 1 ? RND128(c3[1]) : 0);
    int R = pfxr + s;
    int2 e = buckets[flat];
    int* wp = wdest_all + coff + 5 * e.x;
#pragma unroll
    for (int c = 0; c < 5; ++c) wp[c] = (R << 3) + c;
    return;
  }

  // ---- leaf portion ----
  const int lane = threadIdx.x & 63;
  const int wave = threadIdx.x >> 6;
  const int q = lane >> 4;
  const int c = lane & 15;
  const int hh = wave & 1;   // h half: tiles hh*8 .. hh*8+7
  const int gw = wave >> 1;  // group slot within block (0,1)

  bf16x8 wsem[8], wbox[8];
#pragma unroll
  for (int T = 0; T < 8; ++T) {
    const int hb = (hh * 8 + T) * 16 + c;  // A-operand M index = lane&15
    bf16x8 a;
#pragma unroll
    for (int j = 0; j < 8; ++j) a[j] = (bf16_t)0.f;
    if (q < 2) {
#pragma unroll
      for (int j = 0; j < 8; ++j) a[j] = (bf16_t)W_sem[(q * 8 + j) * H_ + hb];
    } else if (q == 2) {
      a[0] = (bf16_t)b_sem[hb];  // k=16 bias slot
    }
    wsem[T] = a;
    bf16x8 b;
#pragma unroll
    for (int j = 0; j < 8; ++j) b[j] = (bf16_t)0.f;
    if (q == 0) {
#pragma unroll
      for (int j = 0; j < 4; ++j) b[j] = (bf16_t)W_box[j * H_ + hb];
      b[4] = (bf16_t)b_box[hb];  // k=4 bias slot
    }
    wbox[T] = b;
  }

  // l5 type-region boundaries (for inline slot->row mapping)
  const int c0v = counters[15], c1v = counters[16], c2v = counters[17];
  const int pfx0 = RND128(c0v);
  const int pfx01 = pfx0 + RND128(c1v);

  const int NG2 = 15705;  // covers all VALID rows (max valid R <= 50253)
  const int gstride = 2048 * 2;  // leaf-block count, NOT gridDim.x
  for (int g = blockIdx.x * 2 + gw; g < NG2; g += gstride) {
    const int ci = g * 16 + c;
    const int R = ci / 5;
    const int c5 = ci - R * 5;
    // inline inverse of dest's l5 mapping: R -> (t,s) -> bucket entry
    int t5, s5;
    if (R < pfx0)       { t5 = 0; s5 = R; }
    else if (R < pfx01) { t5 = 1; s5 = R - pfx0; }
    else                { t5 = 2; s5 = R - pfx01; }
    const int cval = (t5 == 0) ? c0v : (t5 == 1 ? c1v : c2v);
    int row = 0;  // pad slots: any valid row (outputs discarded downstream)
    if (s5 < cval) row = buckets[37488 + t5 * 50000 + s5].y + c5;
    bf16x8 xs, xb;
#pragma unroll
    for (int j = 0; j < 8; ++j) { xs[j] = (bf16_t)0.f; xb[j] = (bf16_t)0.f; }
    if (q < 2) {
      const float4* sp = (const float4*)(leaf_sem + (size_t)row * 16 + q * 8);
      float4 s0 = sp[0], s1 = sp[1];
      xs[0] = (bf16_t)s0.x; xs[1] = (bf16_t)s0.y; xs[2] = (bf16_t)s0.z; xs[3] = (bf16_t)s0.w;
      xs[4] = (bf16_t)s1.x; xs[5] = (bf16_t)s1.y; xs[6] = (bf16_t)s1.z; xs[7] = (bf16_t)s1.w;
    } else if (q == 2) {
      xs[0] = (bf16_t)1.0f;
    }
    if (q == 0) {
      float4 bx = *(const float4*)(leaf_box + (size_t)row * 4);
      xb[0] = (bf16_t)bx.x; xb[1] = (bf16_t)bx.y; xb[2] = (bf16_t)bx.z; xb[3] = (bf16_t)bx.w;
      xb[4] = (bf16_t)1.0f;
    }
    const int rr = R & 127;
    const int sw = (rr >> 1) & 3;
    bf16_t* obase = g5 + (size_t)(R >> 7) * 163840 + rr * 32;
#pragma unroll
    for (int T = 0; T < 8; ++T) {
      f32x4 z = {0.f, 0.f, 0.f, 0.f};
      f32x4 as = __builtin_amdgcn_mfma_f32_16x16x32_bf16(wsem[T], xs, z, 0, 0, 0);
      f32x4 ab = __builtin_amdgcn_mfma_f32_16x16x32_bf16(wbox[T], xb, z, 0, 0, 0);
      bf16x4 o;
#pragma unroll
      for (int r = 0; r < 4; ++r)
        o[r] = (bf16_t)(fmaxf(as[r], 0.f) + fmaxf(ab[r], 0.f));
      // col = hh*128 + q*4 + T*16; e = c5*256+col -> K-panel address
      const int ks = c5 * 8 + hh * 4 + (T >> 1);
      const int pc = (((T & 1) << 1) | (q >> 1)) ^ sw;
      *(bf16x4*)(obase + (size_t)ks * 4096 + (pc << 3) + ((q & 1) << 2)) = o;
    }
  }
}

// ---- shared level-phase body (DEPTH=2 LDS pipeline) -- used by l5 only ----
__device__ __forceinline__ void level_phase(
    int x, const bf16_t* __restrict__ src, bf16_t* __restrict__ dst,
    const int2* __restrict__ bucket, const int* __restrict__ counters,
    const bf16_t* __restrict__ Wt, const float* __restrict__ b_node,
    const float* __restrict__ ibox, const float* __restrict__ W_box,
    const float* __restrict__ b_box, const int* __restrict__ wdest,
    int n_l, int off_l, int cap, int P,
    bf16_t Asm[3][128][32], bf16_t Bsm[3][128][32]) {
  if (x >= 6 * P) return;
  const int t = x / (2 * P);
  const int r2 = x - t * 2 * P;
  const int nblk = r2 / P;
  const int p = r2 - nblk * P;
  const int cnt = counters[t];
  const int tile0 = p * 128;
  if (tile0 >= cnt) return;
  const int pfxr = (t > 0 ? RND128(counters[0]) : 0) + (t > 1 ? RND128(counters[1]) : 0);
  const int2* rd = bucket + (size_t)t * cap;

  const int tid = threadIdx.x;
  const int lane = tid & 63;
  const int wave = tid >> 6;
  const int wm = wave & 1, wn = wave >> 1;
  const int quad = lane >> 4;
  const int l15 = lane & 15;

  const bf16_t* ga0 = src + (size_t)(pfxr + tile0) * 1280 + wave * 1024 + (lane << 3);
  const bf16_t* gb0 = Wt + ((size_t)(t * 2 + nblk) * 40) * 4096 + wave * 1024 + (lane << 3);

  f32x4 acc[4][4];
#pragma unroll
  for (int i = 0; i < 4; ++i)
#pragma unroll
    for (int j = 0; j < 4; ++j) acc[i][j] = (f32x4){0.f, 0.f, 0.f, 0.f};

  const int pcs = (quad ^ ((l15 >> 1) & 3)) * 8;

#define STG2(buf, ks)                                   \
  {                                                     \
    const bf16_t* ga = ga0 + (ks) * 4096;               \
    const bf16_t* gb = gb0 + (ks) * 4096;               \
    bf16_t* la = &Asm[buf][0][0] + wave * 1024;         \
    bf16_t* lb = &Bsm[buf][0][0] + wave * 1024;         \
    gl2lds16(ga, la);                                   \
    gl2lds16(ga + 512, la + 512);                       \
    gl2lds16(gb, lb);                                   \
    gl2lds16(gb + 512, lb + 512);                       \
  }
#define FRG2(bufv)                                                            \
  {                                                                           \
    bf16x8 af[4], bfr[4];                                                     \
    _Pragma("unroll") for (int am = 0; am < 4; ++am)                          \
        af[am] = *(const bf16x8*)(&Asm[bufv][wm * 64 + am * 16 + l15][pcs]);  \
    _Pragma("unroll") for (int bn = 0; bn < 4; ++bn)                          \
        bfr[bn] = *(const bf16x8*)(&Bsm[bufv][wn * 64 + bn * 16 + l15][pcs]); \
    __builtin_amdgcn_s_setprio(1);                                            \
    _Pragma("unroll") for (int am = 0; am < 4; ++am)                          \
        _Pragma("unroll") for (int bn = 0; bn < 4; ++bn)                      \
            acc[am][bn] = __builtin_amdgcn_mfma_f32_16x16x32_bf16(            \
                af[am], bfr[bn], acc[am][bn], 0, 0, 0);                       \
    __builtin_amdgcn_s_setprio(0);                                            \
  }

  STG2(0, 0)
  STG2(1, 1)
  int rbuf = 0, wbuf = 2;
  for (int ks = 0; ks < 38; ++ks) {
    asm volatile("s_waitcnt vmcnt(4)" ::: "memory");
    __builtin_amdgcn_s_barrier();
    {
      bf16x8 af[4], bfr[4];
#pragma unroll
      for (int am = 0; am < 4; ++am)
        af[am] = *(const bf16x8*)(&Asm[rbuf][wm * 64 + am * 16 + l15][pcs]);
#pragma unroll
      for (int bn = 0; bn < 4; ++bn)
        bfr[bn] = *(const bf16x8*)(&Bsm[rbuf][wn * 64 + bn * 16 + l15][pcs]);
      STG2(wbuf, ks + 2)
      __builtin_amdgcn_s_setprio(1);
#pragma unroll
      for (int am = 0; am < 4; ++am)
#pragma unroll
        for (int bn = 0; bn < 4; ++bn)
          acc[am][bn] = __builtin_amdgcn_mfma_f32_16x16x32_bf16(af[am], bfr[bn], acc[am][bn], 0, 0, 0);
      __builtin_amdgcn_s_setprio(0);
    }
    rbuf = (rbuf + 1 == 3) ? 0 : rbuf + 1;
    wbuf = (wbuf + 1 == 3) ? 0 : wbuf + 1;
  }
  asm volatile("s_waitcnt vmcnt(4)" ::: "memory");
  __builtin_amdgcn_s_barrier();
  FRG2(rbuf)
  rbuf = (rbuf + 1 == 3) ? 0 : rbuf + 1;
  asm volatile("s_waitcnt vmcnt(0)" ::: "memory");
  __builtin_amdgcn_s_barrier();
  FRG2(rbuf)
#undef FRG2
#undef STG2

  float wbv[4][6];
#pragma unroll
  for (int bn = 0; bn < 4; ++bn) {
    int col = nblk * 128 + wn * 64 + bn * 16 + l15;
    wbv[bn][0] = W_box[col];
    wbv[bn][1] = W_box[H_ + col];
    wbv[bn][2] = W_box[2 * H_ + col];
    wbv[bn][3] = W_box[3 * H_ + col];
    wbv[bn][4] = b_box[col];
    wbv[bn][5] = b_node[t * H_ + col];
  }
#pragma unroll
  for (int am = 0; am < 4; ++am) {
    int orw_[4]; float4 bxv[4]; bool valid[4];
#pragma unroll
    for (int r = 0; r < 4; ++r) {
      int gidx = tile0 + wm * 64 + am * 16 + quad * 4 + r;
      valid[r] = (gidx < cnt);
      int ic = valid[r] ? gidx : (cnt - 1);
      int orw = rd[ic].x;
      orw_[r] = orw;
      int b = orw / n_l;
      int i = orw - b * n_l;
      bxv[r] = *(const float4*)(ibox + ((size_t)b * NINT + off_l + i) * 4);
    }
    {
      size_t ob[4]; int sw_[4];
#pragma unroll
      for (int r = 0; r < 4; ++r) {
        int wd = wdest[orw_[r]];
        int R = wd >> 3, cc = wd & 7;
        int rr = R & 127;
        ob[r] = (size_t)(R >> 7) * 163840 + (size_t)cc * 32768 + (size_t)rr * 32;
        sw_[r] = (rr >> 1) & 3;
      }
#pragma unroll
      for (int bn = 0; bn < 4; ++bn) {
        int col = nblk * 128 + wn * 64 + bn * 16 + l15;
        int kc2 = col >> 5, qq = (col >> 3) & 3, ww = col & 7;
#pragma unroll
        for (int r = 0; r < 4; ++r) {
          if (!valid[r]) continue;
          float y = fmaxf(acc[am][bn][r] + wbv[bn][5], 0.f);
          float be = fmaf(wbv[bn][0], bxv[r].x,
                     fmaf(wbv[bn][1], bxv[r].y,
                     fmaf(wbv[bn][2], bxv[r].z,
                     fmaf(wbv[bn][3], bxv[r].w, wbv[bn][4]))));
          be = fmaxf(be, 0.f);
          dst[ob[r] + (size_t)kc2 * 4096 + ((qq ^ sw_[r]) << 3) + ww] = (bf16_t)(y + be);
        }
      }
    }
  }
}

// ---- l5 standalone kernel: same-XCD pairing, DEPTH=2 (unchanged) ----
__global__ __launch_bounds__(256) void level5_kernel(
    const bf16_t* __restrict__ src, bf16_t* __restrict__ dst,
    const int2* __restrict__ bucket, const int* __restrict__ counters,
    const bf16_t* __restrict__ Wt, const float* __restrict__ b_node,
    const float* __restrict__ ibox, const float* __restrict__ W_box,
    const float* __restrict__ b_box, const int* __restrict__ wdest,
    int n_l, int off_l, int cap) {
  __shared__ __align__(16) bf16_t Asm[3][128][32];
  __shared__ __align__(16) bf16_t Bsm[3][128][32];
  const int x = blockIdx.x;
  const int p = ((x >> 4) << 3) + (x & 7);  // pair index (A panel)
  const int nblk = (x >> 3) & 1;            // B half
  const int t = blockIdx.y;
  const int P = gridDim.x / 2;
  const int xx = t * 2 * P + nblk * P + p;
  level_phase(xx, src, dst, bucket, counters, Wt, b_node, ibox, W_box, b_box,
              wdest, n_l, off_l, cap, P, Asm, Bsm);
}

// ---- direct small-level kernel: one 16-row slot per block, no LDS, no sync.
// K-loop in groups of 4 k-steps: all 20 loads issued before the 16 MFMAs.
__global__ __launch_bounds__(256, 2) void level_direct(
    const bf16_t* __restrict__ src, bf16_t* __restrict__ dst,
    const int2* __restrict__ bucket, const int* __restrict__ counters,
    const bf16_t* __restrict__ Wt, const float* __restrict__ b_node,
    const float* __restrict__ ibox, const float* __restrict__ W_box,
    const float* __restrict__ b_box, const int* __restrict__ wdest,
    int n_l, int off_l, int cap, int TP) {
  const int sl = blockIdx.x;
  const int t = sl / TP;
  const int s = sl - t * TP;
  const int cnt = counters[t];
  const int tile0 = s * 16;
  if (tile0 >= cnt) return;
  const int pfxr = (t > 0 ? RND128(counters[0]) : 0) + (t > 1 ? RND128(counters[1]) : 0);
  const int2* rd = bucket + (size_t)t * cap;

  const int tid = threadIdx.x;
  const int lane = tid & 63;
  const int wave = tid >> 6;
  const int quad = lane >> 4;
  const int l15 = lane & 15;
  const int pcs = (quad ^ ((l15 >> 1) & 3)) * 8;

  const int Rbase = pfxr + tile0;
  const bf16_t* aptr = src + (size_t)(Rbase >> 7) * 163840 +
                       ((Rbase & 127) + l15) * 32 + pcs;
  const bf16_t* bptr[4];
  int cols[4];
#pragma unroll
  for (int bn = 0; bn < 4; ++bn) {
    int col = wave * 64 + bn * 16 + l15;
    cols[bn] = col;
    bptr[bn] = Wt + (size_t)(t * 2 + (col >> 7)) * 163840 + (col & 127) * 32 + pcs;
  }

  f32x4 acc[4];
#pragma unroll
  for (int bn = 0; bn < 4; ++bn) acc[bn] = (f32x4){0.f, 0.f, 0.f, 0.f};
#pragma unroll
  for (int g = 0; g < 10; ++g) {
    bf16x8 af[4], b0[4], b1[4], b2[4], b3[4];
#pragma unroll
    for (int i = 0; i < 4; ++i) {
      const size_t o = (size_t)(g * 4 + i) * 4096;
      af[i] = *(const bf16x8*)(aptr + o);
      b0[i] = *(const bf16x8*)(bptr[0] + o);
      b1[i] = *(const bf16x8*)(bptr[1] + o);
      b2[i] = *(const bf16x8*)(bptr[2] + o);
      b3[i] = *(const bf16x8*)(bptr[3] + o);
    }
#pragma unroll
    for (int i = 0; i < 4; ++i) {
      acc[0] = __builtin_amdgcn_mfma_f32_16x16x32_bf16(af[i], b0[i], acc[0], 0, 0, 0);
      acc[1] = __builtin_amdgcn_mfma_f32_16x16x32_bf16(af[i], b1[i], acc[1], 0, 0, 0);
      acc[2] = __builtin_amdgcn_mfma_f32_16x16x32_bf16(af[i], b2[i], acc[2], 0, 0, 0);
      acc[3] = __builtin_amdgcn_mfma_f32_16x16x32_bf16(af[i], b3[i], acc[3], 0, 0, 0);
    }
  }

  // ---- epilogue (C/D: col=l15, row=quad*4+r) ----
  int orw_[4]; float4 bxv[4]; bool valid[4];
#pragma unroll
  for (int r = 0; r < 4; ++r) {
    int gidx = tile0 + quad * 4 + r;
    valid[r] = (gidx < cnt);
    int ic = valid[r] ? gidx : (cnt - 1);
    int orw = rd[ic].x;
    orw_[r] = orw;
    int b = orw / n_l;
    int i = orw - b * n_l;
    bxv[r] = *(const float4*)(ibox + ((size_t)b * NINT + off_l + i) * 4);
  }
  if (wdest) {
    size_t ob[4]; int swz[4];
#pragma unroll
    for (int r = 0; r < 4; ++r) {
      int wd = wdest[orw_[r]];
      int R = wd >> 3, cc = wd & 7;
      int rr = R & 127;
      ob[r] = (size_t)(R >> 7) * 163840 + (size_t)cc * 32768 + (size_t)rr * 32;
      swz[r] = (rr >> 1) & 3;
    }
#pragma unroll
    for (int bn = 0; bn < 4; ++bn) {
      int col = cols[bn];
      float w0 = W_box[col], w1 = W_box[H_ + col], w2 = W_box[2 * H_ + col];
      float w3 = W_box[3 * H_ + col], w4 = b_box[col];
      float bn5 = b_node[t * H_ + col];
      int kc2 = col >> 5, qq = (col >> 3) & 3, ww = col & 7;
#pragma unroll
      for (int r = 0; r < 4; ++r) {
        if (!valid[r]) continue;
        float y = fmaxf(acc[bn][r] + bn5, 0.f);
        float be = fmaf(w0, bxv[r].x, fmaf(w1, bxv[r].y,
                   fmaf(w2, bxv[r].z, fmaf(w3, bxv[r].w, w4))));
        be = fmaxf(be, 0.f);
        dst[ob[r] + (size_t)kc2 * 4096 + ((size_t)(qq ^ swz[r]) << 3) + ww] =
            (bf16_t)(y + be);
      }
    }
  } else {
#pragma unroll
    for (int bn = 0; bn < 4; ++bn) {
      int col = cols[bn];
      float w0 = W_box[col], w1 = W_box[H_ + col], w2 = W_box[2 * H_ + col];
      float w3 = W_box[3 * H_ + col], w4 = b_box[col];
      float bn5 = b_node[t * H_ + col];
#pragma unroll
      for (int r = 0; r < 4; ++r) {
        if (!valid[r]) continue;
        float y = fmaxf(acc[bn][r] + bn5, 0.f);
        float be = fmaf(w0, bxv[r].x, fmaf(w1, bxv[r].y,
                   fmaf(w2, bxv[r].z, fmaf(w3, bxv[r].w, w4))));
        be = fmaxf(be, 0.f);
        dst[(size_t)orw_[r] * H_ + col] = (bf16_t)(y + be);  // f0 row-major
      }
    }
  }
}

__global__ __launch_bounds__(256) void head_kernel(
    const bf16_t* __restrict__ f0, const float* __restrict__ eps,
    const float* __restrict__ W1, const float* __restrict__ b1,
    const float* __restrict__ Wmu, const float* __restrict__ bmu,
    const float* __restrict__ Wvar, const float* __restrict__ bvar,
    float* __restrict__ out) {
  __shared__ float root[256];
  __shared__ float enc[256];
  int b = blockIdx.x, h = threadIdx.x;
  root[h] = (float)f0[b * H_ + h];
  __syncthreads();
  float a = b1[h];
  for (int k = 0; k < 256; ++k) a = fmaf(root[k], W1[k * H_ + h], a);
  enc[h] = fmaxf(a, 0.f);
  __syncthreads();
  float m = bmu[h], lv = bvar[h];
  for (int k = 0; k < 256; ++k) {
    float e = enc[k];
    m = fmaf(e, Wmu[k * H_ + h], m);
    lv = fmaf(e, Wvar[k * H_ + h], lv);
  }
  float stdv = expf(0.5f * lv);
  float kld = 1.f + lv - m * m - expf(lv);
  out[b * 512 + h] = eps[b * H_ + h] * stdv + m;
  out[b * 512 + 256 + h] = kld;
}

extern "C" void kernel_launch(void* const* d_in, const int* in_sizes, int n_in,
                              void* d_out, int out_size, void* d_ws, size_t ws_size,
                              hipStream_t stream) {
  const float* leaf_box     = (const float*)d_in[0];
  const float* leaf_sem     = (const float*)d_in[1];
  const float* internal_box = (const float*)d_in[2];
  const int*   node_type    = (const int*)d_in[3];
  const float* eps          = (const float*)d_in[4];
  const float* W_box        = (const float*)d_in[5];
  const float* b_box        = (const float*)d_in[6];
  const float* W_sem        = (const float*)d_in[7];
  const float* b_sem        = (const float*)d_in[8];
  const float* W_node       = (const float*)d_in[9];
  const float* b_node       = (const float*)d_in[10];
  const float* W1           = (const float*)d_in[11];
  const float* b1           = (const float*)d_in[12];
  const float* Wmu          = (const float*)d_in[13];
  const float* bmu          = (const float*)d_in[14];
  const float* Wvar         = (const float*)d_in[15];
  const float* bvar         = (const float*)d_in[16];
  float* out = (float*)d_out;

  char* p = (char*)d_ws;
  auto alloc = [&](size_t bytes) {
    char* r = p;
    p += (bytes + 255) & ~(size_t)255;
    return r;
  };
  const int n_tab[6] = {1, 5, 25, 125, 625, 3125};
  bf16_t* Wt = (bf16_t*)alloc((size_t)3 * 2 * 40 * 4096 * 2);  // 1.97 MB, K-panel
  bf16_t* f0 = (bf16_t*)alloc((size_t)B_ * H_ * 2);
  bf16_t* G[6];  // G[l] = K-panel child-concat matrix for level-l parents
  for (int l = 0; l <= 5; ++l)
    G[l] = (bf16_t*)alloc(((size_t)B_ * n_tab[l] + 384) * 1280 * 2);
  int* counters  = (int*)alloc(128 * 4);
  int2* buckets  = (int2*)alloc((size_t)187488 * 8);
  int* wdest_all = (int*)alloc((size_t)62480 * 4);

  hipLaunchKernelGGL(prep_kernel, dim3(240), dim3(256), 0, stream, W_node, Wt, counters);
  hipLaunchKernelGGL(bucket_kernel, dim3((B_ * NINT + 255) / 256), dim3(256), 0, stream,
                     node_type, counters, buckets);
  hipLaunchKernelGGL(leafdest_kernel, dim3(2048 + 147), dim3(256), 0, stream,
                     leaf_box, leaf_sem, W_box, b_box, W_sem, b_sem,
                     buckets, counters, wdest_all, G[5]);

  // l5: standalone (pairing + K-panel, LDS pipeline)
  {
    int cap = B_ * n_tab[5];
    int tiles = (cap + 127) / 128;
    int tiles8 = (tiles + 7) & ~7;
    hipLaunchKernelGGL(level5_kernel, dim3(2 * tiles8, 3), dim3(256), 0, stream,
                       G[5], G[4], buckets + 37488, counters + 15,
                       Wt, b_node, internal_box, W_box, b_box,
                       wdest_all + 12480, 3125, 781, cap);
  }

  // l4..l0: direct-MFMA kernels, one 16-row slot per block, stream-ordered
  const int lvl_base[6] = {0, 48, 288, 1488, 7488, 37488};
  const int off_tab[6]  = {0, 1, 6, 31, 156, 781};
  const int woff[6]     = {0, 0, 80, 480, 2480, 12480};  // wdest region of child level l
  for (int l = 4; l >= 0; --l) {
    int TP = n_tab[l];
    const int* wdp = (l >= 1) ? (wdest_all + woff[l]) : nullptr;
    bf16_t* dstp = (l >= 1) ? G[l - 1] : f0;
    hipLaunchKernelGGL(level_direct, dim3(3 * TP), dim3(256), 0, stream,
                       G[l], dstp, buckets + lvl_base[l], counters + l * 3,
                       Wt, b_node, internal_box, W_box, b_box, wdp,
                       n_tab[l], off_tab[l], B_ * n_tab[l], TP);
  }
  hipLaunchKernelGGL(head_kernel, dim3(16), dim3(256), 0, stream,
                     f0, eps, W1, b1, Wmu, bmu, Wvar, bvar, out);
}

// Round 17
// 339.218 us; speedup vs baseline: 1.0410x; 1.0410x over previous
//
#include <hip/hip_runtime.h>

// RecursiveEncoder on MI355X. B=16, H=256, S=16, C=5, L=6, N_LEAF=15625, N_INT=3906.
// R22: l4 moves from level_direct (16-row blocks: 640KB Wt re-read per block,
//      ~392MB L2 traffic for a 25.6MB level) to the parameterized level5_kernel
//      (128x128 LDS pipeline + same-XCD pairing: 16x better B reuse). Launcher
//      -only change; grid (160,3) keeps the pairing decode (mult of 16); G[4]
//      pad covers 128-aligned tiles; wdest epilogue path is l4's. l3..l0 stay
//      level_direct (traffic trivial). Leaf closed (4 structures, constant
//      2.1 TB/s); boundary-count closed (below noise). Rest = R21.

#define B_ 16
#define H_ 256
#define NLEAF 15625
#define NINT 3906
#define RND128(x) (((x) + 127) & ~127)

typedef __bf16 bf16_t;
typedef bf16_t bf16x8 __attribute__((ext_vector_type(8)));
typedef bf16_t bf16x4 __attribute__((ext_vector_type(4)));
typedef float f32x4 __attribute__((ext_vector_type(4)));

__device__ __forceinline__ void gl2lds16(const bf16_t* g, bf16_t* l) {
  __builtin_amdgcn_global_load_lds((const __attribute__((address_space(1))) void*)g,
                                   (__attribute__((address_space(3))) void*)l,
                                   16, 0, 0);
}

// Wt K-panel layout: panel (t*2+half) of 128 h-rows; elem (h,k) at
// panel*40*4096 + (k>>5)*4096 + (h&127)*32 + (chunk^swz)*8 + (k&7).
__global__ __launch_bounds__(256) void prep_kernel(const float* __restrict__ W_node,
                                                   bf16_t* __restrict__ Wt,
                                                   int* __restrict__ counters) {
  if (blockIdx.x == 0 && threadIdx.x < 18) counters[threadIdx.x] = 0;
  const int t = blockIdx.x / 80;
  const int kc = blockIdx.x % 80;
  const int h = threadIdx.x;
  const int half = h >> 7, r = h & 127;
  const int sw = (r >> 1) & 3;
  const float* srcp = W_node + (size_t)t * 1280 * 256 + h;
  bf16_t* base = Wt + ((size_t)(t * 2 + half) * 40) * 4096 + r * 32;
#pragma unroll
  for (int k0 = kc * 16; k0 < kc * 16 + 16; k0 += 8) {
    bf16x8 v;
#pragma unroll
    for (int j = 0; j < 8; ++j) v[j] = (bf16_t)srcp[(size_t)(k0 + j) * 256];
    const int ks = k0 >> 5;
    const int q = (k0 >> 3) & 3;
    *(bf16x8*)(base + (size_t)ks * 4096 + ((q ^ sw) << 3)) = v;
  }
}

// LDS-aggregated bucketing (block-local order preserved -> decent locality).
__global__ __launch_bounds__(256) void bucket_kernel(const int* __restrict__ node_type,
                                                     int* __restrict__ counters,
                                                     int2* __restrict__ buckets) {
  __shared__ int lcnt[18];
  __shared__ int lbase[18];
  const int tid = threadIdx.x;
  if (tid < 18) lcnt[tid] = 0;
  __syncthreads();

  int idx = blockIdx.x * 256 + tid;
  bool active = idx < B_ * NINT;
  int t = 0, key = 0, mypos = 0;
  int2 e;
  int base = 0, nl_cap = 0;
  if (active) {
    int b = idx / NINT;
    int j = idx - b * NINT;
    int l, off;
    if (j >= 781)      { l = 5; off = 781; }
    else if (j >= 156) { l = 4; off = 156; }
    else if (j >= 31)  { l = 3; off = 31; }
    else if (j >= 6)   { l = 2; off = 6; }
    else if (j >= 1)   { l = 1; off = 1; }
    else               { l = 0; off = 0; }
    const int n_tab[6]    = {1, 5, 25, 125, 625, 3125};
    const int nn_tab[6]   = {5, 25, 125, 625, 3125, 15625};
    const int base_tab[6] = {0, 48, 288, 1488, 7488, 37488};
    int n_l = n_tab[l], nn = nn_tab[l];
    t = node_type[idx];
    int i = j - off;
    e.x = b * n_l + i;
    e.y = b * nn + 5 * i;
    base = base_tab[l];
    nl_cap = B_ * n_l;
    key = l * 3 + t;
    mypos = atomicAdd(&lcnt[key], 1);
  }
  __syncthreads();
  if (tid < 18) {
    int c = lcnt[tid];
    lbase[tid] = c ? atomicAdd(&counters[tid], c) : 0;
  }
  __syncthreads();
  if (active) {
    buckets[base + t * nl_cap + lbase[key] + mypos] = e;
  }
}

// MFMA leaf + folded wdest scatter. Blocks < 2048: leaf compute (wave handles
// 16 consecutive G_5 chunk-slots; leaf row derived INLINE from buckets via the
// inverse of dest's mapping). Blocks >= 2048: the l<5 wdest scatter.
__global__ __launch_bounds__(256) void leafdest_kernel(
    const float* __restrict__ leaf_box, const float* __restrict__ leaf_sem,
    const float* __restrict__ W_box, const float* __restrict__ b_box,
    const float* __restrict__ W_sem, const float* __restrict__ b_sem,
    const int2* __restrict__ buckets, const int* __restrict__ counters,
    int* __restrict__ wdest_all, bf16_t* __restrict__ g5) {
  if (blockIdx.x >= 2048) {
    // ---- dest portion: parents at levels 0..4 -> children wdest slots ----
    int flat = (blockIdx.x - 2048) * 256 + threadIdx.x;
    if (flat >= 37488) return;
    int l, base, cap, coff;
    if (flat >= 7488)       { l = 4; base = 7488;  cap = 10000; coff = 12480; }
    else if (flat >= 1488)  { l = 3; base = 1488;  cap = 2000;  coff = 2480; }
    else if (flat >= 288)   { l = 2; base = 288;   cap = 400;   coff = 480; }
    else if (flat >= 48)    { l = 1; base = 48;    cap = 80;    coff = 80; }
    else                    { l = 0; base = 0;     cap = 16;    coff = 0; }
    int rel = flat - base;
    int t = (rel >= 2 * cap) ? 2 : (rel >= cap ? 1 : 0);
    int s = rel - t * cap;
    const int* c3 = counters + l * 3;
    if (s >= c3[t]) return;
    int pfxr = (t > 0 ? RND128(c3[0]) : 0) + (t > 1 ? RND128(c3[1]) : 0);
    int R = pfxr + s;
    int2 e = buckets[flat];
    int* wp = wdest_all + coff + 5 * e.x;
#pragma unroll
    for (int c = 0; c < 5; ++c) wp[c] = (R << 3) + c;
    return;
  }

  // ---- leaf portion ----
  const int lane = threadIdx.x & 63;
  const int wave = threadIdx.x >> 6;
  const int q = lane >> 4;
  const int c = lane & 15;
  const int hh = wave & 1;   // h half: tiles hh*8 .. hh*8+7
  const int gw = wave >> 1;  // group slot within block (0,1)

  bf16x8 wsem[8], wbox[8];
#pragma unroll
  for (int T = 0; T < 8; ++T) {
    const int hb = (hh * 8 + T) * 16 + c;  // A-operand M index = lane&15
    bf16x8 a;
#pragma unroll
    for (int j = 0; j < 8; ++j) a[j] = (bf16_t)0.f;
    if (q < 2) {
#pragma unroll
      for (int j = 0; j < 8; ++j) a[j] = (bf16_t)W_sem[(q * 8 + j) * H_ + hb];
    } else if (q == 2) {
      a[0] = (bf16_t)b_sem[hb];  // k=16 bias slot
    }
    wsem[T] = a;
    bf16x8 b;
#pragma unroll
    for (int j = 0; j < 8; ++j) b[j] = (bf16_t)0.f;
    if (q == 0) {
#pragma unroll
      for (int j = 0; j < 4; ++j) b[j] = (bf16_t)W_box[j * H_ + hb];
      b[4] = (bf16_t)b_box[hb];  // k=4 bias slot
    }
    wbox[T] = b;
  }

  // l5 type-region boundaries (for inline slot->row mapping)
  const int c0v = counters[15], c1v = counters[16], c2v = counters[17];
  const int pfx0 = RND128(c0v);
  const int pfx01 = pfx0 + RND128(c1v);

  const int NG2 = 15705;  // covers all VALID rows (max valid R <= 50253)
  const int gstride = 2048 * 2;  // leaf-block count, NOT gridDim.x
  for (int g = blockIdx.x * 2 + gw; g < NG2; g += gstride) {
    const int ci = g * 16 + c;
    const int R = ci / 5;
    const int c5 = ci - R * 5;
    // inline inverse of dest's l5 mapping: R -> (t,s) -> bucket entry
    int t5, s5;
    if (R < pfx0)       { t5 = 0; s5 = R; }
    else if (R < pfx01) { t5 = 1; s5 = R - pfx0; }
    else                { t5 = 2; s5 = R - pfx01; }
    const int cval = (t5 == 0) ? c0v : (t5 == 1 ? c1v : c2v);
    int row = 0;  // pad slots: any valid row (outputs discarded downstream)
    if (s5 < cval) row = buckets[37488 + t5 * 50000 + s5].y + c5;
    bf16x8 xs, xb;
#pragma unroll
    for (int j = 0; j < 8; ++j) { xs[j] = (bf16_t)0.f; xb[j] = (bf16_t)0.f; }
    if (q < 2) {
      const float4* sp = (const float4*)(leaf_sem + (size_t)row * 16 + q * 8);
      float4 s0 = sp[0], s1 = sp[1];
      xs[0] = (bf16_t)s0.x; xs[1] = (bf16_t)s0.y; xs[2] = (bf16_t)s0.z; xs[3] = (bf16_t)s0.w;
      xs[4] = (bf16_t)s1.x; xs[5] = (bf16_t)s1.y; xs[6] = (bf16_t)s1.z; xs[7] = (bf16_t)s1.w;
    } else if (q == 2) {
      xs[0] = (bf16_t)1.0f;
    }
    if (q == 0) {
      float4 bx = *(const float4*)(leaf_box + (size_t)row * 4);
      xb[0] = (bf16_t)bx.x; xb[1] = (bf16_t)bx.y; xb[2] = (bf16_t)bx.z; xb[3] = (bf16_t)bx.w;
      xb[4] = (bf16_t)1.0f;
    }
    const int rr = R & 127;
    const int sw = (rr >> 1) & 3;
    bf16_t* obase = g5 + (size_t)(R >> 7) * 163840 + rr * 32;
#pragma unroll
    for (int T = 0; T < 8; ++T) {
      f32x4 z = {0.f, 0.f, 0.f, 0.f};
      f32x4 as = __builtin_amdgcn_mfma_f32_16x16x32_bf16(wsem[T], xs, z, 0, 0, 0);
      f32x4 ab = __builtin_amdgcn_mfma_f32_16x16x32_bf16(wbox[T], xb, z, 0, 0, 0);
      bf16x4 o;
#pragma unroll
      for (int r = 0; r < 4; ++r)
        o[r] = (bf16_t)(fmaxf(as[r], 0.f) + fmaxf(ab[r], 0.f));
      // col = hh*128 + q*4 + T*16; e = c5*256+col -> K-panel address
      const int ks = c5 * 8 + hh * 4 + (T >> 1);
      const int pc = (((T & 1) << 1) | (q >> 1)) ^ sw;
      *(bf16x4*)(obase + (size_t)ks * 4096 + (pc << 3) + ((q & 1) << 2)) = o;
    }
  }
}

// ---- shared level-phase body (DEPTH=2 LDS pipeline) -- l5 AND l4 ----
__device__ __forceinline__ void level_phase(
    int x, const bf16_t* __restrict__ src, bf16_t* __restrict__ dst,
    const int2* __restrict__ bucket, const int* __restrict__ counters,
    const bf16_t* __restrict__ Wt, const float* __restrict__ b_node,
    const float* __restrict__ ibox, const float* __restrict__ W_box,
    const float* __restrict__ b_box, const int* __restrict__ wdest,
    int n_l, int off_l, int cap, int P,
    bf16_t Asm[3][128][32], bf16_t Bsm[3][128][32]) {
  if (x >= 6 * P) return;
  const int t = x / (2 * P);
  const int r2 = x - t * 2 * P;
  const int nblk = r2 / P;
  const int p = r2 - nblk * P;
  const int cnt = counters[t];
  const int tile0 = p * 128;
  if (tile0 >= cnt) return;
  const int pfxr = (t > 0 ? RND128(counters[0]) : 0) + (t > 1 ? RND128(counters[1]) : 0);
  const int2* rd = bucket + (size_t)t * cap;

  const int tid = threadIdx.x;
  const int lane = tid & 63;
  const int wave = tid >> 6;
  const int wm = wave & 1, wn = wave >> 1;
  const int quad = lane >> 4;
  const int l15 = lane & 15;

  const bf16_t* ga0 = src + (size_t)(pfxr + tile0) * 1280 + wave * 1024 + (lane << 3);
  const bf16_t* gb0 = Wt + ((size_t)(t * 2 + nblk) * 40) * 4096 + wave * 1024 + (lane << 3);

  f32x4 acc[4][4];
#pragma unroll
  for (int i = 0; i < 4; ++i)
#pragma unroll
    for (int j = 0; j < 4; ++j) acc[i][j] = (f32x4){0.f, 0.f, 0.f, 0.f};

  const int pcs = (quad ^ ((l15 >> 1) & 3)) * 8;

#define STG2(buf, ks)                                   \
  {                                                     \
    const bf16_t* ga = ga0 + (ks) * 4096;               \
    const bf16_t* gb = gb0 + (ks) * 4096;               \
    bf16_t* la = &Asm[buf][0][0] + wave * 1024;         \
    bf16_t* lb = &Bsm[buf][0][0] + wave * 1024;         \
    gl2lds16(ga, la);                                   \
    gl2lds16(ga + 512, la + 512);                       \
    gl2lds16(gb, lb);                                   \
    gl2lds16(gb + 512, lb + 512);                       \
  }
#define FRG2(bufv)                                                            \
  {                                                                           \
    bf16x8 af[4], bfr[4];                                                     \
    _Pragma("unroll") for (int am = 0; am < 4; ++am)                          \
        af[am] = *(const bf16x8*)(&Asm[bufv][wm * 64 + am * 16 + l15][pcs]);  \
    _Pragma("unroll") for (int bn = 0; bn < 4; ++bn)                          \
        bfr[bn] = *(const bf16x8*)(&Bsm[bufv][wn * 64 + bn * 16 + l15][pcs]); \
    __builtin_amdgcn_s_setprio(1);                                            \
    _Pragma("unroll") for (int am = 0; am < 4; ++am)                          \
        _Pragma("unroll") for (int bn = 0; bn < 4; ++bn)                      \
            acc[am][bn] = __builtin_amdgcn_mfma_f32_16x16x32_bf16(            \
                af[am], bfr[bn], acc[am][bn], 0, 0, 0);                       \
    __builtin_amdgcn_s_setprio(0);                                            \
  }

  STG2(0, 0)
  STG2(1, 1)
  int rbuf = 0, wbuf = 2;
  for (int ks = 0; ks < 38; ++ks) {
    asm volatile("s_waitcnt vmcnt(4)" ::: "memory");
    __builtin_amdgcn_s_barrier();
    {
      bf16x8 af[4], bfr[4];
#pragma unroll
      for (int am = 0; am < 4; ++am)
        af[am] = *(const bf16x8*)(&Asm[rbuf][wm * 64 + am * 16 + l15][pcs]);
#pragma unroll
      for (int bn = 0; bn < 4; ++bn)
        bfr[bn] = *(const bf16x8*)(&Bsm[rbuf][wn * 64 + bn * 16 + l15][pcs]);
      STG2(wbuf, ks + 2)
      __builtin_amdgcn_s_setprio(1);
#pragma unroll
      for (int am = 0; am < 4; ++am)
#pragma unroll
        for (int bn = 0; bn < 4; ++bn)
          acc[am][bn] = __builtin_amdgcn_mfma_f32_16x16x32_bf16(af[am], bfr[bn], acc[am][bn], 0, 0, 0);
      __builtin_amdgcn_s_setprio(0);
    }
    rbuf = (rbuf + 1 == 3) ? 0 : rbuf + 1;
    wbuf = (wbuf + 1 == 3) ? 0 : wbuf + 1;
  }
  asm volatile("s_waitcnt vmcnt(4)" ::: "memory");
  __builtin_amdgcn_s_barrier();
  FRG2(rbuf)
  rbuf = (rbuf + 1 == 3) ? 0 : rbuf + 1;
  asm volatile("s_waitcnt vmcnt(0)" ::: "memory");
  __builtin_amdgcn_s_barrier();
  FRG2(rbuf)
#undef FRG2
#undef STG2

  float wbv[4][6];
#pragma unroll
  for (int bn = 0; bn < 4; ++bn) {
    int col = nblk * 128 + wn * 64 + bn * 16 + l15;
    wbv[bn][0] = W_box[col];
    wbv[bn][1] = W_box[H_ + col];
    wbv[bn][2] = W_box[2 * H_ + col];
    wbv[bn][3] = W_box[3 * H_ + col];
    wbv[bn][4] = b_box[col];
    wbv[bn][5] = b_node[t * H_ + col];
  }
#pragma unroll
  for (int am = 0; am < 4; ++am) {
    int orw_[4]; float4 bxv[4]; bool valid[4];
#pragma unroll
    for (int r = 0; r < 4; ++r) {
      int gidx = tile0 + wm * 64 + am * 16 + quad * 4 + r;
      valid[r] = (gidx < cnt);
      int ic = valid[r] ? gidx : (cnt - 1);
      int orw = rd[ic].x;
      orw_[r] = orw;
      int b = orw / n_l;
      int i = orw - b * n_l;
      bxv[r] = *(const float4*)(ibox + ((size_t)b * NINT + off_l + i) * 4);
    }
    {
      size_t ob[4]; int sw_[4];
#pragma unroll
      for (int r = 0; r < 4; ++r) {
        int wd = wdest[orw_[r]];
        int R = wd >> 3, cc = wd & 7;
        int rr = R & 127;
        ob[r] = (size_t)(R >> 7) * 163840 + (size_t)cc * 32768 + (size_t)rr * 32;
        sw_[r] = (rr >> 1) & 3;
      }
#pragma unroll
      for (int bn = 0; bn < 4; ++bn) {
        int col = nblk * 128 + wn * 64 + bn * 16 + l15;
        int kc2 = col >> 5, qq = (col >> 3) & 3, ww = col & 7;
#pragma unroll
        for (int r = 0; r < 4; ++r) {
          if (!valid[r]) continue;
          float y = fmaxf(acc[am][bn][r] + wbv[bn][5], 0.f);
          float be = fmaf(wbv[bn][0], bxv[r].x,
                     fmaf(wbv[bn][1], bxv[r].y,
                     fmaf(wbv[bn][2], bxv[r].z,
                     fmaf(wbv[bn][3], bxv[r].w, wbv[bn][4]))));
          be = fmaxf(be, 0.f);
          dst[ob[r] + (size_t)kc2 * 4096 + ((qq ^ sw_[r]) << 3) + ww] = (bf16_t)(y + be);
        }
      }
    }
  }
}

// ---- big-level kernel (l5, l4): same-XCD pairing, DEPTH=2 ----
__global__ __launch_bounds__(256) void level5_kernel(
    const bf16_t* __restrict__ src, bf16_t* __restrict__ dst,
    const int2* __restrict__ bucket, const int* __restrict__ counters,
    const bf16_t* __restrict__ Wt, const float* __restrict__ b_node,
    const float* __restrict__ ibox, const float* __restrict__ W_box,
    const float* __restrict__ b_box, const int* __restrict__ wdest,
    int n_l, int off_l, int cap) {
  __shared__ __align__(16) bf16_t Asm[3][128][32];
  __shared__ __align__(16) bf16_t Bsm[3][128][32];
  const int x = blockIdx.x;
  const int p = ((x >> 4) << 3) + (x & 7);  // pair index (A panel)
  const int nblk = (x >> 3) & 1;            // B half
  const int t = blockIdx.y;
  const int P = gridDim.x / 2;
  const int xx = t * 2 * P + nblk * P + p;
  level_phase(xx, src, dst, bucket, counters, Wt, b_node, ibox, W_box, b_box,
              wdest, n_l, off_l, cap, P, Asm, Bsm);
}

// ---- direct small-level kernel: one 16-row slot per block, no LDS, no sync.
__global__ __launch_bounds__(256, 2) void level_direct(
    const bf16_t* __restrict__ src, bf16_t* __restrict__ dst,
    const int2* __restrict__ bucket, const int* __restrict__ counters,
    const bf16_t* __restrict__ Wt, const float* __restrict__ b_node,
    const float* __restrict__ ibox, const float* __restrict__ W_box,
    const float* __restrict__ b_box, const int* __restrict__ wdest,
    int n_l, int off_l, int cap, int TP) {
  const int sl = blockIdx.x;
  const int t = sl / TP;
  const int s = sl - t * TP;
  const int cnt = counters[t];
  const int tile0 = s * 16;
  if (tile0 >= cnt) return;
  const int pfxr = (t > 0 ? RND128(counters[0]) : 0) + (t > 1 ? RND128(counters[1]) : 0);
  const int2* rd = bucket + (size_t)t * cap;

  const int tid = threadIdx.x;
  const int lane = tid & 63;
  const int wave = tid >> 6;
  const int quad = lane >> 4;
  const int l15 = lane & 15;
  const int pcs = (quad ^ ((l15 >> 1) & 3)) * 8;

  const int Rbase = pfxr + tile0;
  const bf16_t* aptr = src + (size_t)(Rbase >> 7) * 163840 +
                       ((Rbase & 127) + l15) * 32 + pcs;
  const bf16_t* bptr[4];
  int cols[4];
#pragma unroll
  for (int bn = 0; bn < 4; ++bn) {
    int col = wave * 64 + bn * 16 + l15;
    cols[bn] = col;
    bptr[bn] = Wt + (size_t)(t * 2 + (col >> 7)) * 163840 + (col & 127) * 32 + pcs;
  }

  f32x4 acc[4];
#pragma unroll
  for (int bn = 0; bn < 4; ++bn) acc[bn] = (f32x4){0.f, 0.f, 0.f, 0.f};
#pragma unroll
  for (int g = 0; g < 10; ++g) {
    bf16x8 af[4], b0[4], b1[4], b2[4], b3[4];
#pragma unroll
    for (int i = 0; i < 4; ++i) {
      const size_t o = (size_t)(g * 4 + i) * 4096;
      af[i] = *(const bf16x8*)(aptr + o);
      b0[i] = *(const bf16x8*)(bptr[0] + o);
      b1[i] = *(const bf16x8*)(bptr[1] + o);
      b2[i] = *(const bf16x8*)(bptr[2] + o);
      b3[i] = *(const bf16x8*)(bptr[3] + o);
    }
#pragma unroll
    for (int i = 0; i < 4; ++i) {
      acc[0] = __builtin_amdgcn_mfma_f32_16x16x32_bf16(af[i], b0[i], acc[0], 0, 0, 0);
      acc[1] = __builtin_amdgcn_mfma_f32_16x16x32_bf16(af[i], b1[i], acc[1], 0, 0, 0);
      acc[2] = __builtin_amdgcn_mfma_f32_16x16x32_bf16(af[i], b2[i], acc[2], 0, 0, 0);
      acc[3] = __builtin_amdgcn_mfma_f32_16x16x32_bf16(af[i], b3[i], acc[3], 0, 0, 0);
    }
  }

  // ---- epilogue (C/D: col=l15, row=quad*4+r) ----
  int orw_[4]; float4 bxv[4]; bool valid[4];
#pragma unroll
  for (int r = 0; r < 4; ++r) {
    int gidx = tile0 + quad * 4 + r;
    valid[r] = (gidx < cnt);
    int ic = valid[r] ? gidx : (cnt - 1);
    int orw = rd[ic].x;
    orw_[r] = orw;
    int b = orw / n_l;
    int i = orw - b * n_l;
    bxv[r] = *(const float4*)(ibox + ((size_t)b * NINT + off_l + i) * 4);
  }
  if (wdest) {
    size_t ob[4]; int swz[4];
#pragma unroll
    for (int r = 0; r < 4; ++r) {
      int wd = wdest[orw_[r]];
      int R = wd >> 3, cc = wd & 7;
      int rr = R & 127;
      ob[r] = (size_t)(R >> 7) * 163840 + (size_t)cc * 32768 + (size_t)rr * 32;
      swz[r] = (rr >> 1) & 3;
    }
#pragma unroll
    for (int bn = 0; bn < 4; ++bn) {
      int col = cols[bn];
      float w0 = W_box[col], w1 = W_box[H_ + col], w2 = W_box[2 * H_ + col];
      float w3 = W_box[3 * H_ + col], w4 = b_box[col];
      float bn5 = b_node[t * H_ + col];
      int kc2 = col >> 5, qq = (col >> 3) & 3, ww = col & 7;
#pragma unroll
      for (int r = 0; r < 4; ++r) {
        if (!valid[r]) continue;
        float y = fmaxf(acc[bn][r] + bn5, 0.f);
        float be = fmaf(w0, bxv[r].x, fmaf(w1, bxv[r].y,
                   fmaf(w2, bxv[r].z, fmaf(w3, bxv[r].w, w4))));
        be = fmaxf(be, 0.f);
        dst[ob[r] + (size_t)kc2 * 4096 + ((size_t)(qq ^ swz[r]) << 3) + ww] =
            (bf16_t)(y + be);
      }
    }
  } else {
#pragma unroll
    for (int bn = 0; bn < 4; ++bn) {
      int col = cols[bn];
      float w0 = W_box[col], w1 = W_box[H_ + col], w2 = W_box[2 * H_ + col];
      float w3 = W_box[3 * H_ + col], w4 = b_box[col];
      float bn5 = b_node[t * H_ + col];
#pragma unroll
      for (int r = 0; r < 4; ++r) {
        if (!valid[r]) continue;
        float y = fmaxf(acc[bn][r] + bn5, 0.f);
        float be = fmaf(w0, bxv[r].x, fmaf(w1, bxv[r].y,
                   fmaf(w2, bxv[r].z, fmaf(w3, bxv[r].w, w4))));
        be = fmaxf(be, 0.f);
        dst[(size_t)orw_[r] * H_ + col] = (bf16_t)(y + be);  // f0 row-major
      }
    }
  }
}

__global__ __launch_bounds__(256) void head_kernel(
    const bf16_t* __restrict__ f0, const float* __restrict__ eps,
    const float* __restrict__ W1, const float* __restrict__ b1,
    const float* __restrict__ Wmu, const float* __restrict__ bmu,
    const float* __restrict__ Wvar, const float* __restrict__ bvar,
    float* __restrict__ out) {
  __shared__ float root[256];
  __shared__ float enc[256];
  int b = blockIdx.x, h = threadIdx.x;
  root[h] = (float)f0[b * H_ + h];
  __syncthreads();
  float a = b1[h];
  for (int k = 0; k < 256; ++k) a = fmaf(root[k], W1[k * H_ + h], a);
  enc[h] = fmaxf(a, 0.f);
  __syncthreads();
  float m = bmu[h], lv = bvar[h];
  for (int k = 0; k < 256; ++k) {
    float e = enc[k];
    m = fmaf(e, Wmu[k * H_ + h], m);
    lv = fmaf(e, Wvar[k * H_ + h], lv);
  }
  float stdv = expf(0.5f * lv);
  float kld = 1.f + lv - m * m - expf(lv);
  out[b * 512 + h] = eps[b * H_ + h] * stdv + m;
  out[b * 512 + 256 + h] = kld;
}

extern "C" void kernel_launch(void* const* d_in, const int* in_sizes, int n_in,
                              void* d_out, int out_size, void* d_ws, size_t ws_size,
                              hipStream_t stream) {
  const float* leaf_box     = (const float*)d_in[0];
  const float* leaf_sem     = (const float*)d_in[1];
  const float* internal_box = (const float*)d_in[2];
  const int*   node_type    = (const int*)d_in[3];
  const float* eps          = (const float*)d_in[4];
  const float* W_box        = (const float*)d_in[5];
  const float* b_box        = (const float*)d_in[6];
  const float* W_sem        = (const float*)d_in[7];
  const float* b_sem        = (const float*)d_in[8];
  const float* W_node       = (const float*)d_in[9];
  const float* b_node       = (const float*)d_in[10];
  const float* W1           = (const float*)d_in[11];
  const float* b1           = (const float*)d_in[12];
  const float* Wmu          = (const float*)d_in[13];
  const float* bmu          = (const float*)d_in[14];
  const float* Wvar         = (const float*)d_in[15];
  const float* bvar         = (const float*)d_in[16];
  float* out = (float*)d_out;

  char* p = (char*)d_ws;
  auto alloc = [&](size_t bytes) {
    char* r = p;
    p += (bytes + 255) & ~(size_t)255;
    return r;
  };
  const int n_tab[6] = {1, 5, 25, 125, 625, 3125};
  bf16_t* Wt = (bf16_t*)alloc((size_t)3 * 2 * 40 * 4096 * 2);  // 1.97 MB, K-panel
  bf16_t* f0 = (bf16_t*)alloc((size_t)B_ * H_ * 2);
  bf16_t* G[6];  // G[l] = K-panel child-concat matrix for level-l parents
  for (int l = 0; l <= 5; ++l)
    G[l] = (bf16_t*)alloc(((size_t)B_ * n_tab[l] + 384) * 1280 * 2);
  int* counters  = (int*)alloc(128 * 4);
  int2* buckets  = (int2*)alloc((size_t)187488 * 8);
  int* wdest_all = (int*)alloc((size_t)62480 * 4);

  hipLaunchKernelGGL(prep_kernel, dim3(240), dim3(256), 0, stream, W_node, Wt, counters);
  hipLaunchKernelGGL(bucket_kernel, dim3((B_ * NINT + 255) / 256), dim3(256), 0, stream,
                     node_type, counters, buckets);
  hipLaunchKernelGGL(leafdest_kernel, dim3(2048 + 147), dim3(256), 0, stream,
                     leaf_box, leaf_sem, W_box, b_box, W_sem, b_sem,
                     buckets, counters, wdest_all, G[5]);

  // l5: pipelined (pairing + K-panel)
  {
    int cap = B_ * n_tab[5];
    int tiles8 = (((cap + 127) / 128) + 7) & ~7;
    hipLaunchKernelGGL(level5_kernel, dim3(2 * tiles8, 3), dim3(256), 0, stream,
                       G[5], G[4], buckets + 37488, counters + 15,
                       Wt, b_node, internal_box, W_box, b_box,
                       wdest_all + 12480, 3125, 781, cap);
  }
  // l4: pipelined too (R22: kills level_direct's 640KB-per-16-rows Wt re-read)
  {
    int cap = B_ * n_tab[4];
    int tiles8 = (((cap + 127) / 128) + 7) & ~7;  // 80 -> grid (160,3), mult of 16
    hipLaunchKernelGGL(level5_kernel, dim3(2 * tiles8, 3), dim3(256), 0, stream,
                       G[4], G[3], buckets + 7488, counters + 12,
                       Wt, b_node, internal_box, W_box, b_box,
                       wdest_all + 2480, 625, 156, cap);
  }

  // l3..l0: direct-MFMA kernels, one 16-row slot per block, stream-ordered
  const int lvl_base[6] = {0, 48, 288, 1488, 7488, 37488};
  const int off_tab[6]  = {0, 1, 6, 31, 156, 781};
  const int woff[6]     = {0, 0, 80, 480, 2480, 12480};  // wdest region of child level l
  for (int l = 3; l >= 0; --l) {
    int TP = n_tab[l];
    const int* wdp = (l >= 1) ? (wdest_all + woff[l]) : nullptr;
    bf16_t* dstp = (l >= 1) ? G[l - 1] : f0;
    hipLaunchKernelGGL(level_direct, dim3(3 * TP), dim3(256), 0, stream,
                       G[l], dstp, buckets + lvl_base[l], counters + l * 3,
                       Wt, b_node, internal_box, W_box, b_box, wdp,
                       n_tab[l], off_tab[l], B_ * n_tab[l], TP);
  }
  hipLaunchKernelGGL(head_kernel, dim3(16), dim3(256), 0, stream,
                     f0, eps, W1, b1, Wmu, bmu, Wvar, bvar, out);
}